// Round 4
// baseline (122.253 us; speedup 1.0000x reference)
//
#include <hip/hip_runtime.h>
#include <cstdint>
#include <cstddef>

// PNNLayer collapse:  out[n,:] = dists[n,:] @ P + embeds[n,:] @ W2 + b
//   P = (1/32) * (embeds[anchorset_id] @ W1)   [32 x 64] constant
//   W1 = W_hidden[0:64], W2 = W_hidden[64:128]
// dtypes (verified round 3): all float tensors f32, ids int32, output f32.
//
// Round-4 design: LDS-free. Thread = 1 node x 64 dims (64 acc VGPRs).
//   - x (dists/embeds row) streams through VGPRs, 8 floats/chunk, prefetch-rotated.
//   - weights are wave-uniform -> s_load_dwordx16 into SGPRs; v_fma takes 1 SGPR src.
//   DS pipe usage: zero (round-3 model: DS was the 11.7us ceiling vs HBM 10.2 / VALU 7.8).
//   Block = 64 (one wave, no barriers) -> 1563 blocks -> 7:6 tail vs 2:1 at 391 blocks.

#define N_NODES 100000
#define DIM     64

// ---- kernel 1: P[a][d] = (1/32) * sum_e embeds[aid[a]][e] * W[e][d] ----
__global__ __launch_bounds__(256) void pnn_prep(
    const float* __restrict__ embeds,   // [N,64] f32
    const float* __restrict__ W,        // [128,64] f32
    const int*   __restrict__ aid,      // [32]
    float*       __restrict__ P)        // [32,64]
{
    const int t = blockIdx.x * 256 + threadIdx.x;   // 0..2047
    const int a = t >> 6, d = t & 63;
    const float* se = embeds + (size_t)aid[a] * DIM;
    float s = 0.f;
    #pragma unroll
    for (int e = 0; e < DIM; ++e) s += se[e] * W[e * DIM + d];
    P[t] = s * (1.0f / 32.0f);
}

// ---- kernel 2: one node per thread, weights via scalar pipe ----
__global__ __launch_bounds__(64) void pnn_main(
    const float* __restrict__ embeds,
    const float* __restrict__ dists,
    const float* __restrict__ P,        // [32,64] prescaled
    const float* __restrict__ W,        // full [128,64]; W2 = W + 4096
    const float* __restrict__ bias,
    float* __restrict__ out)            // [N,64] f32
{
    const int n = blockIdx.x * 64 + threadIdx.x;
    const bool valid = (n < N_NODES);
    const size_t nc = valid ? (size_t)n : (size_t)(N_NODES - 1);  // clamp; store guarded

    float acc[DIM];
    #pragma unroll
    for (int d = 0; d < DIM; ++d) acc[d] = bias[d];   // uniform -> s_load + v_mov

    const float4* drow = (const float4*)(dists  + nc * 32);          // 8 float4
    const float4* erow = (const float4*)(embeds + nc * (size_t)DIM); // 16 float4
    const float*  W2   = W + 64 * DIM;

    // prefetch: dists chunk 0 and embeds chunk 0
    float4 x0 = drow[0], x1 = drow[1];
    float4 p0 = erow[0], p1 = erow[1];

    // ---- anchor phase: 4 chunks x 8 anchors ----
    #pragma unroll 1
    for (int eb = 0; eb < 4; ++eb) {
        // branch-free prefetch (index wraps in-bounds on last iter; value unused)
        float4 nx0 = drow[(2 * eb + 2) & 7];
        float4 nx1 = drow[(2 * eb + 3) & 7];
        const float xs[8] = {x0.x, x0.y, x0.z, x0.w, x1.x, x1.y, x1.z, x1.w};
        const float* wr = P + eb * 8 * DIM;   // uniform -> scalar loads
        #pragma unroll
        for (int j = 0; j < 8; ++j) {
            #pragma unroll
            for (int d = 0; d < DIM; ++d)
                acc[d] += xs[j] * wr[j * DIM + d];
        }
        x0 = nx0; x1 = nx1;
    }

    // ---- embed phase: 8 chunks x 8 dims of the input row ----
    #pragma unroll 1
    for (int eb = 0; eb < 8; ++eb) {
        float4 nx0 = erow[(2 * eb + 2) & 15];
        float4 nx1 = erow[(2 * eb + 3) & 15];
        const float xs[8] = {p0.x, p0.y, p0.z, p0.w, p1.x, p1.y, p1.z, p1.w};
        const float* wr = W2 + eb * 8 * DIM;  // uniform -> scalar loads
        #pragma unroll
        for (int j = 0; j < 8; ++j) {
            #pragma unroll
            for (int d = 0; d < DIM; ++d)
                acc[d] += xs[j] * wr[j * DIM + d];
        }
        p0 = nx0; p1 = nx1;
    }

    if (valid) {
        float4* po = (float4*)(out + (size_t)n * DIM);
        #pragma unroll
        for (int g = 0; g < 16; ++g)
            po[g] = make_float4(acc[4 * g], acc[4 * g + 1], acc[4 * g + 2], acc[4 * g + 3]);
    }
}

extern "C" void kernel_launch(void* const* d_in, const int* in_sizes, int n_in,
                              void* d_out, int out_size, void* d_ws, size_t ws_size,
                              hipStream_t stream) {
    const float* embeds = (const float*)d_in[0];   // [100000,64] f32
    const float* dists  = (const float*)d_in[1];   // [100000,32] f32
    const float* W      = (const float*)d_in[2];   // [128,64] f32
    const float* bias   = (const float*)d_in[3];   // [64] f32
    const int*   aid    = (const int*)d_in[4];     // [32] int32
    float* out = (float*)d_out;                    // [100000,64] f32

    float* P = (float*)d_ws;                       // 2048 floats

    pnn_prep<<<8, 256, 0, stream>>>(embeds, W, aid, P);
    const int grid = (N_NODES + 63) / 64;          // 1563
    pnn_main<<<grid, 64, 0, stream>>>(embeds, dists, P, W, bias, out);
}

// Round 5
// 102.933 us; speedup vs baseline: 1.1877x; 1.1877x over previous
//
#include <hip/hip_runtime.h>
#include <cstdint>
#include <cstddef>

// PNNLayer collapse:  out[n,:] = dists[n,:] @ P + embeds[n,:] @ W2 + b
//   P = (1/32) * (embeds[anchorset_id] @ W1)   [32 x 64] constant
//   => one GEMM: X [100000 x 96] @ Wcat [96 x 64], X = [dists | embeds],
//      Wcat = [P ; W2].  dtypes: all f32 in/out (verified R3), ids int32.
//
// R4 post-mortem: SGPR-weight path 83% scalar-stalled (VALUBusy 16%).
// R5: MFMA with split-bf16 (hi/lo, 3-term) -> compute pipes ~free, HBM-bound.

#define N_NODES 100000
#define DIM     64
#define NTILES  1563     // ceil(100000 / 64)
#define GRIDM   782      // 3.05 blocks/CU; each block does 2 tiles
#define AS_K    104      // LDS A-row stride in ushorts (208 B, 16B-aligned, ~2-way banks)

typedef short bf16x8 __attribute__((ext_vector_type(8)));   // 8 bf16 = 4 VGPRs
typedef float f32x4  __attribute__((ext_vector_type(4)));   // MFMA acc

__device__ __forceinline__ unsigned short f2bf(float f) {
    union { float f; unsigned u; } c; c.f = f;
    return (unsigned short)((c.u + 0x7fffu + ((c.u >> 16) & 1u)) >> 16);  // RNE
}
__device__ __forceinline__ float bf2f(unsigned short h) {
    union { unsigned u; float f; } c; c.u = ((unsigned)h) << 16; return c.f;
}

// ---- kernel 1: P[k][n] = (1/32) * sum_e embeds[aid[k]][e] * W[e][n]  (f32) ----
__global__ __launch_bounds__(256) void pnn_prep(
    const float* __restrict__ embeds, const float* __restrict__ W,
    const int* __restrict__ aid, float* __restrict__ P)
{
    const int t = blockIdx.x * 256 + threadIdx.x;   // 0..2047
    const int a = t >> 6, d = t & 63;
    const float* se = embeds + (size_t)aid[a] * DIM;
    float s = 0.f;
    #pragma unroll
    for (int e = 0; e < DIM; ++e) s += se[e] * W[e * DIM + d];
    P[t] = s * (1.0f / 32.0f);
}

// ---- kernel 2: pack Wcat into B-fragment order, split hi/lo bf16 ----
// fragB flat idx = (((ks*4 + nt)*2 + pl)*64 + lane)*8 + j
// element = Wcat[k = ks*32 + (lane>>4)*8 + j][n = nt*16 + (lane&15)]
__global__ __launch_bounds__(256) void pnn_pack(
    const float* __restrict__ P, const float* __restrict__ W,
    unsigned short* __restrict__ fragB)
{
    const int idx = blockIdx.x * 256 + threadIdx.x;  // 0..12287 (grid 48)
    const int j  = idx & 7;
    const int ln = (idx >> 3) & 63;
    const int pl = (idx >> 9) & 1;
    const int nt = (idx >> 10) & 3;
    const int ks = idx >> 12;
    const int k  = ks * 32 + (ln >> 4) * 8 + j;
    const int n  = nt * 16 + (ln & 15);
    const float w = (k < 32) ? P[k * 64 + n]            // anchor part (prescaled)
                             : W[(k + 32) * 64 + n];    // W2 rows 64..127
    unsigned short h = f2bf(w);
    if (pl) h = f2bf(w - bf2f(h));                      // lo plane
    fragB[idx] = h;
}

// ---- kernel 3: MFMA main. block = 256 (4 waves), 64 nodes/tile, 2 tiles/block ----
__global__ __launch_bounds__(256, 3) void pnn_main(
    const float* __restrict__ embeds,
    const float* __restrict__ dists,
    const unsigned short* __restrict__ fragB,
    const float* __restrict__ bias,
    float* __restrict__ out)
{
    // A staging: As[plane][mtile][m][k], row stride AS_K ushorts
    __shared__ unsigned short As[2][4][16][AS_K];       // 26624 B

    const int tid  = threadIdx.x;
    const int wave = tid >> 6;
    const int lane = tid & 63;
    const int quad = lane >> 4;
    const int col  = lane & 15;

    // B fragments: 24 x 16B coalesced loads, live in 96 VGPRs for whole kernel
    bf16x8 Bf[3][4][2];
    {
        const bf16x8* Bg = (const bf16x8*)fragB;
        #pragma unroll
        for (int ks = 0; ks < 3; ++ks)
            #pragma unroll
            for (int nt = 0; nt < 4; ++nt)
                #pragma unroll
                for (int pl = 0; pl < 2; ++pl)
                    Bf[ks][nt][pl] = Bg[((ks * 4 + nt) * 2 + pl) * 64 + lane];
    }
    float bias_n[4];
    #pragma unroll
    for (int nt = 0; nt < 4; ++nt) bias_n[nt] = bias[nt * 16 + col];

    for (int tile = blockIdx.x; tile < NTILES; tile += GRIDM) {
        const int n0 = tile * 64;

        // ---- stage X tile (64 nodes x 96 k) as hi/lo bf16 in A-frag row order ----
        float4 dv[2], ev[4];
        {
            const float4* dg = (const float4*)(dists + (size_t)n0 * 32);
            #pragma unroll
            for (int i = 0; i < 2; ++i) {
                const int f = i * 256 + tid;            // float4 idx, 8 per node
                dv[i] = (n0 + (f >> 3) < N_NODES) ? dg[f] : make_float4(0.f,0.f,0.f,0.f);
            }
            const float4* eg = (const float4*)(embeds + (size_t)n0 * 64);
            #pragma unroll
            for (int i = 0; i < 4; ++i) {
                const int f = i * 256 + tid;            // float4 idx, 16 per node
                ev[i] = (n0 + (f >> 4) < N_NODES) ? eg[f] : make_float4(0.f,0.f,0.f,0.f);
            }
        }
        #pragma unroll
        for (int i = 0; i < 2; ++i) {                   // dists -> k = 0..31
            const int f  = i * 256 + tid;
            const int nd = f >> 3, k0 = (f & 7) * 4;
            unsigned short* hp = &As[0][nd >> 4][nd & 15][k0];
            unsigned short* lp = &As[1][nd >> 4][nd & 15][k0];
            const float4 v = dv[i];
            unsigned short h0=f2bf(v.x),h1=f2bf(v.y),h2=f2bf(v.z),h3=f2bf(v.w);
            *(unsigned*)hp       = (unsigned)h0 | ((unsigned)h1 << 16);
            *(unsigned*)(hp + 2) = (unsigned)h2 | ((unsigned)h3 << 16);
            unsigned short l0=f2bf(v.x-bf2f(h0)),l1=f2bf(v.y-bf2f(h1)),
                           l2=f2bf(v.z-bf2f(h2)),l3=f2bf(v.w-bf2f(h3));
            *(unsigned*)lp       = (unsigned)l0 | ((unsigned)l1 << 16);
            *(unsigned*)(lp + 2) = (unsigned)l2 | ((unsigned)l3 << 16);
        }
        #pragma unroll
        for (int i = 0; i < 4; ++i) {                   // embeds -> k = 32..95
            const int f  = i * 256 + tid;
            const int nd = f >> 4, k0 = 32 + (f & 15) * 4;
            unsigned short* hp = &As[0][nd >> 4][nd & 15][k0];
            unsigned short* lp = &As[1][nd >> 4][nd & 15][k0];
            const float4 v = ev[i];
            unsigned short h0=f2bf(v.x),h1=f2bf(v.y),h2=f2bf(v.z),h3=f2bf(v.w);
            *(unsigned*)hp       = (unsigned)h0 | ((unsigned)h1 << 16);
            *(unsigned*)(hp + 2) = (unsigned)h2 | ((unsigned)h3 << 16);
            unsigned short l0=f2bf(v.x-bf2f(h0)),l1=f2bf(v.y-bf2f(h1)),
                           l2=f2bf(v.z-bf2f(h2)),l3=f2bf(v.w-bf2f(h3));
            *(unsigned*)lp       = (unsigned)l0 | ((unsigned)l1 << 16);
            *(unsigned*)(lp + 2) = (unsigned)l2 | ((unsigned)l3 << 16);
        }
        __syncthreads();

        // ---- compute: wave owns m-tile = wave (16 nodes), all 64 dims ----
        f32x4 acc[4];
        #pragma unroll
        for (int nt = 0; nt < 4; ++nt) {
            const float b = bias_n[nt];
            acc[nt][0] = b; acc[nt][1] = b; acc[nt][2] = b; acc[nt][3] = b;
        }
        #pragma unroll
        for (int ks = 0; ks < 3; ++ks) {
            const bf16x8 Ahi = *(const bf16x8*)&As[0][wave][col][ks * 32 + quad * 8];
            const bf16x8 Alo = *(const bf16x8*)&As[1][wave][col][ks * 32 + quad * 8];
            #pragma unroll
            for (int nt = 0; nt < 4; ++nt) {
                acc[nt] = __builtin_amdgcn_mfma_f32_16x16x32_bf16(Ahi, Bf[ks][nt][0], acc[nt], 0, 0, 0);
                acc[nt] = __builtin_amdgcn_mfma_f32_16x16x32_bf16(Ahi, Bf[ks][nt][1], acc[nt], 0, 0, 0);
                acc[nt] = __builtin_amdgcn_mfma_f32_16x16x32_bf16(Alo, Bf[ks][nt][0], acc[nt], 0, 0, 0);
            }
        }

        // ---- store: D row = node (quad*4 + r), col = dim (nt*16 + col) ----
        #pragma unroll
        for (int r = 0; r < 4; ++r) {
            const int node = n0 + wave * 16 + quad * 4 + r;
            if (node < N_NODES) {
                float* po = out + (size_t)node * DIM + col;
                #pragma unroll
                for (int nt = 0; nt < 4; ++nt) po[nt * 16] = acc[nt][r];
            }
        }
        __syncthreads();   // protect As before next iteration's staging
    }
}

extern "C" void kernel_launch(void* const* d_in, const int* in_sizes, int n_in,
                              void* d_out, int out_size, void* d_ws, size_t ws_size,
                              hipStream_t stream) {
    const float* embeds = (const float*)d_in[0];   // [100000,64] f32
    const float* dists  = (const float*)d_in[1];   // [100000,32] f32
    const float* W      = (const float*)d_in[2];   // [128,64] f32
    const float* bias   = (const float*)d_in[3];   // [64] f32
    const int*   aid    = (const int*)d_in[4];     // [32] int32
    float* out = (float*)d_out;                    // [100000,64] f32

    float*          P     = (float*)d_ws;                      // 2048 f32
    unsigned short* fragB = (unsigned short*)((char*)d_ws + 2048 * sizeof(float)); // 12288 bf16

    pnn_prep<<<8, 256, 0, stream>>>(embeds, W, aid, P);
    pnn_pack<<<48, 256, 0, stream>>>(P, W, fragB);
    pnn_main<<<GRIDM, 256, 0, stream>>>(embeds, dists, fragB, bias, out);
}

// Round 7
// 94.142 us; speedup vs baseline: 1.2986x; 1.0934x over previous
//
#include <hip/hip_runtime.h>
#include <cstdint>
#include <cstddef>

// PNNLayer collapse:  out[n,:] = dists[n,:] @ P + embeds[n,:] @ W2 + b
//   P = (1/32) * (embeds[anchorset_id] @ W1)   [32 x 64] constant
//   => one GEMM: X [100000 x 96] @ Wcat [96 x 64], Wcat = [P ; W2]
// dtypes (verified R3): all f32 in/out, ids int32. MFMA via split-bf16 (3-term).
//
// R6 post-mortem: fused prep only covered 1024 of 8192 W2 fragment entries
// (4 blocks instead of 32) -> 7/8 of fragB stayed 0xAA poison (~0 as bf16)
// -> out ~= dists@P, absmax 3.86 = max|emb@W2+b|. Fix: grid 8+32 = 40 blocks.
// Main kernel unchanged from R6 (LDS B-frags, persistent, prefetch).

#define N_NODES 100000
#define DIM     64
#define NTILES  1563     // ceil(100000 / 64)
#define GRID    768      // exactly 3 blocks/CU resident; ~2 tiles/block
#define AS_K    104      // A-tile row stride in ushorts (16B-aligned, spread banks)

typedef short bf16x8 __attribute__((ext_vector_type(8)));   // 8 bf16 = 4 VGPRs
typedef float f32x4  __attribute__((ext_vector_type(4)));   // MFMA acc

__device__ __forceinline__ unsigned short f2bf(float f) {
    union { float f; unsigned u; } c; c.f = f;
    return (unsigned short)((c.u + 0x7fffu + ((c.u >> 16) & 1u)) >> 16);  // RNE
}
__device__ __forceinline__ float bf2f(unsigned short h) {
    union { unsigned u; float f; } c; c.u = ((unsigned)h) << 16; return c.f;
}
__device__ __forceinline__ unsigned long long pack4h(float a, float b, float c, float d) {
    unsigned short h0 = f2bf(a), h1 = f2bf(b), h2 = f2bf(c), h3 = f2bf(d);
    return (unsigned long long)h0 | ((unsigned long long)h1 << 16) |
           ((unsigned long long)h2 << 32) | ((unsigned long long)h3 << 48);
}
__device__ __forceinline__ unsigned long long pack4l(float a, float b, float c, float d) {
    unsigned short l0 = f2bf(a - bf2f(f2bf(a))), l1 = f2bf(b - bf2f(f2bf(b)));
    unsigned short l2 = f2bf(c - bf2f(f2bf(c))), l3 = f2bf(d - bf2f(f2bf(d)));
    return (unsigned long long)l0 | ((unsigned long long)l1 << 16) |
           ((unsigned long long)l2 << 32) | ((unsigned long long)l3 << 48);
}

// ---- kernel 1 (fused prep+pack): blocks 0-7 compute P -> fragB(ks=0, 4096
//      entries, 2 per thread); blocks 8-39 pack W2 -> fragB(ks=1,2; 8192
//      entries, 1 per thread).
// fragB flat idx = (((ks*4+nt)*2+pl)*64 + lane)*8 + j ;
// element = Wcat[k = ks*32 + (lane>>4)*8 + j][n = nt*16 + (lane&15)]
__global__ __launch_bounds__(256) void pnn_prep(
    const float* __restrict__ embeds, const float* __restrict__ W,
    const int* __restrict__ aid, unsigned short* __restrict__ fragB)
{
    const int b = blockIdx.x, tid = threadIdx.x;
    if (b < 8) {
        const int t = b * 256 + tid;          // 0..2047 : one P entry each
        const int a = t >> 6, d = t & 63;     // a = k (wave-uniform), d = n
        const float* se = embeds + (size_t)aid[a] * DIM;
        float s = 0.f;
        #pragma unroll
        for (int e = 0; e < DIM; ++e) s += se[e] * W[e * DIM + d];  // W1 rows 0..63
        s *= (1.0f / 32.0f);
        const int j = a & 7, quad = a >> 3;           // k = a (ks = 0)
        const int nt = d >> 4, col = d & 15;
        const int lane = quad * 16 + col;
        const unsigned short hi = f2bf(s);
        fragB[((nt * 2 + 0) * 64 + lane) * 8 + j] = hi;
        fragB[((nt * 2 + 1) * 64 + lane) * 8 + j] = f2bf(s - bf2f(hi));
    } else {
        const int w = (b - 8) * 256 + tid;    // 0..8191 : one W2 entry each
        const int j    = w & 7;
        const int lane = (w >> 3) & 63;
        const int pl   = (w >> 9) & 1;
        const int nt   = (w >> 10) & 3;
        const int ks   = 1 + (w >> 12);       // 1..2
        const int k = ks * 32 + (lane >> 4) * 8 + j;   // 32..95
        const int n = nt * 16 + (lane & 15);
        const float v = W[(k + 32) * DIM + n];         // W2 rows 64..127
        unsigned short h = f2bf(v);
        if (pl) h = f2bf(v - bf2f(h));
        fragB[(((ks * 4 + nt) * 2 + pl) * 64 + lane) * 8 + j] = h;
    }
}

#define LOAD_TILE(m0)                                                          \
    do {                                                                       \
        const float4* dg = (const float4*)(dists + (size_t)(m0) * 32);         \
        _Pragma("unroll")                                                      \
        for (int i = 0; i < 2; ++i) {                                          \
            const int f = i * 256 + tid;                                       \
            dv[i] = ((m0) + (f >> 3) < N_NODES) ? dg[f]                        \
                                                : make_float4(0.f,0.f,0.f,0.f);\
        }                                                                      \
        const float4* eg = (const float4*)(embeds + (size_t)(m0) * 64);        \
        _Pragma("unroll")                                                      \
        for (int i = 0; i < 4; ++i) {                                          \
            const int f = i * 256 + tid;                                       \
            ev[i] = ((m0) + (f >> 4) < N_NODES) ? eg[f]                        \
                                                : make_float4(0.f,0.f,0.f,0.f);\
        }                                                                      \
    } while (0)

// ---- kernel 2: persistent MFMA main, block = 256 (4 waves), 64 nodes/tile ----
__global__ __launch_bounds__(256, 3) void pnn_main(
    const float* __restrict__ embeds,
    const float* __restrict__ dists,
    const unsigned short* __restrict__ fragB,
    const float* __restrict__ bias,
    float* __restrict__ out)
{
    __shared__ __align__(16) unsigned short sB[12288];          // 24 KB B-frags
    __shared__ __align__(16) unsigned short As[2][4][16][AS_K]; // 26 KB A-tile
    // total 50 KB static -> 3 blocks/CU (LDS-capped)

    const int tid  = threadIdx.x;
    const int wave = tid >> 6;
    const int lane = tid & 63;
    const int quad = lane >> 4;
    const int col  = lane & 15;

    // stage all B fragments into LDS (coalesced; consumed via ds_read_b128)
    #pragma unroll
    for (int i = 0; i < 6; ++i)
        ((uint4*)sB)[i * 256 + tid] = ((const uint4*)fragB)[i * 256 + tid];

    float bias_n[4];
    #pragma unroll
    for (int nt = 0; nt < 4; ++nt) bias_n[nt] = bias[nt * 16 + col];

    int tile = blockIdx.x;
    float4 dv[2], ev[4];
    LOAD_TILE(tile * 64);                       // first tile's globals

    for (; tile < NTILES; tile += GRID) {
        const int n0 = tile * 64;

        // ---- convert regs -> As (hi/lo planes), ds_write_b64 (2-way banks) ----
        #pragma unroll
        for (int i = 0; i < 2; ++i) {           // dists -> k = 0..31
            const int f  = i * 256 + tid;
            const int nd = f >> 3, k0 = (f & 7) * 4;
            const float4 v = dv[i];
            *(unsigned long long*)&As[0][nd >> 4][nd & 15][k0] = pack4h(v.x, v.y, v.z, v.w);
            *(unsigned long long*)&As[1][nd >> 4][nd & 15][k0] = pack4l(v.x, v.y, v.z, v.w);
        }
        #pragma unroll
        for (int i = 0; i < 4; ++i) {           // embeds -> k = 32..95
            const int f  = i * 256 + tid;
            const int nd = f >> 4, k0 = 32 + (f & 15) * 4;
            const float4 v = ev[i];
            *(unsigned long long*)&As[0][nd >> 4][nd & 15][k0] = pack4h(v.x, v.y, v.z, v.w);
            *(unsigned long long*)&As[1][nd >> 4][nd & 15][k0] = pack4l(v.x, v.y, v.z, v.w);
        }
        __syncthreads();

        // ---- prefetch next tile's globals (in flight through MFMA+store) ----
        const int t2 = tile + GRID;
        if (t2 < NTILES) {                      // block-uniform branch
            LOAD_TILE(t2 * 64);
        }

        // ---- compute: wave owns 16 nodes (m-tile = wave), all 64 dims ----
        f32x4 acc[4];
        #pragma unroll
        for (int nt = 0; nt < 4; ++nt) {
            const float bb = bias_n[nt];
            acc[nt][0] = bb; acc[nt][1] = bb; acc[nt][2] = bb; acc[nt][3] = bb;
        }
        const bf16x8* Bl = (const bf16x8*)sB;
        #pragma unroll
        for (int ks = 0; ks < 3; ++ks) {
            const bf16x8 Ahi = *(const bf16x8*)&As[0][wave][col][ks * 32 + quad * 8];
            const bf16x8 Alo = *(const bf16x8*)&As[1][wave][col][ks * 32 + quad * 8];
            #pragma unroll
            for (int nt = 0; nt < 4; ++nt) {
                const bf16x8 Bh = Bl[((ks * 4 + nt) * 2 + 0) * 64 + lane];
                const bf16x8 Bo = Bl[((ks * 4 + nt) * 2 + 1) * 64 + lane];
                acc[nt] = __builtin_amdgcn_mfma_f32_16x16x32_bf16(Ahi, Bh, acc[nt], 0, 0, 0);
                acc[nt] = __builtin_amdgcn_mfma_f32_16x16x32_bf16(Ahi, Bo, acc[nt], 0, 0, 0);
                acc[nt] = __builtin_amdgcn_mfma_f32_16x16x32_bf16(Alo, Bh, acc[nt], 0, 0, 0);
            }
        }

        // ---- store: D row = node (quad*4 + r), col = dim (nt*16 + col) ----
        #pragma unroll
        for (int r = 0; r < 4; ++r) {
            const int node = n0 + wave * 16 + quad * 4 + r;
            if (node < N_NODES) {
                float* po = out + (size_t)node * DIM + col;
                #pragma unroll
                for (int nt = 0; nt < 4; ++nt) po[nt * 16] = acc[nt][r];
            }
        }
        __syncthreads();   // As reusable for next iteration's staging
    }
}

extern "C" void kernel_launch(void* const* d_in, const int* in_sizes, int n_in,
                              void* d_out, int out_size, void* d_ws, size_t ws_size,
                              hipStream_t stream) {
    const float* embeds = (const float*)d_in[0];   // [100000,64] f32
    const float* dists  = (const float*)d_in[1];   // [100000,32] f32
    const float* W      = (const float*)d_in[2];   // [128,64] f32
    const float* bias   = (const float*)d_in[3];   // [64] f32
    const int*   aid    = (const int*)d_in[4];     // [32] int32
    float* out = (float*)d_out;                    // [100000,64] f32

    unsigned short* fragB = (unsigned short*)d_ws; // 12288 bf16 = 24.6 KB

    pnn_prep<<<40, 256, 0, stream>>>(embeds, W, aid, fragB);
    pnn_main<<<GRID, 256, 0, stream>>>(embeds, dists, fragB, bias, out);
}